// Round 1
// baseline (1354.082 us; speedup 1.0000x reference)
//
#include <hip/hip_runtime.h>
#include <math.h>

#define B_   16
#define L_   2048
#define DMOD 64
#define E_   128
#define S_   16
#define NLAY 4
#define NCLS 35
// BL = 32768

// DPP row_shr add: invalid lanes contribute 0 (bound_ctrl=true, old=0)
#define DPPADD(x, ctrl) \
  x += __int_as_float(__builtin_amdgcn_update_dpp(0, __float_as_int(x), ctrl, 0xf, 0xf, true))

// ---------------- init: h = x*W_proj + b_proj ; zero mean ----------------
__global__ void k_init(const float* __restrict__ x, const float* __restrict__ Wp,
                       const float* __restrict__ bp, float* __restrict__ h,
                       float* __restrict__ mean) {
  int i = blockIdx.x * 256 + threadIdx.x;   // grid covers BL*64 exactly
  if (i < B_ * DMOD) mean[i] = 0.f;
  int d = i & 63;
  int r = i >> 6;
  h[i] = x[r] * Wp[d] + bp[d];
}

// ---------------- LN + xz GEMM: xz[r,e] = sum_d LN(h)[r,d] * W_in[e,d] ----------------
__global__ __launch_bounds__(256) void k_lnxz(
    const float* __restrict__ h, const float* __restrict__ lgm,
    const float* __restrict__ lbt, const float* __restrict__ W,
    float* __restrict__ xz) {
  __shared__ float xl[32 * 68];
  int tid = threadIdx.x;
  int row = tid >> 3, j = tid & 7;
  size_t gr = (size_t)blockIdx.x * 32 + row;
  const float4* hp = (const float4*)(h + gr * 64 + j * 8);
  float4 v0 = hp[0], v1 = hp[1];
  float s = v0.x + v0.y + v0.z + v0.w + v1.x + v1.y + v1.z + v1.w;
  s += __shfl_xor(s, 1, 8); s += __shfl_xor(s, 2, 8); s += __shfl_xor(s, 4, 8);
  float mu = s * (1.f / 64.f);
  float d0, q = 0.f;
  d0 = v0.x - mu; q += d0 * d0;  d0 = v0.y - mu; q += d0 * d0;
  d0 = v0.z - mu; q += d0 * d0;  d0 = v0.w - mu; q += d0 * d0;
  d0 = v1.x - mu; q += d0 * d0;  d0 = v1.y - mu; q += d0 * d0;
  d0 = v1.z - mu; q += d0 * d0;  d0 = v1.w - mu; q += d0 * d0;
  q += __shfl_xor(q, 1, 8); q += __shfl_xor(q, 2, 8); q += __shfl_xor(q, 4, 8);
  float rs = rsqrtf(q * (1.f / 64.f) + 1e-5f);
  const float4* gp = (const float4*)(lgm + j * 8);
  const float4* bp2 = (const float4*)(lbt + j * 8);
  float4 g0 = gp[0], g1 = gp[1], b0 = bp2[0], b1 = bp2[1];
  float* xw = &xl[row * 68 + j * 8];
  xw[0] = (v0.x - mu) * rs * g0.x + b0.x;
  xw[1] = (v0.y - mu) * rs * g0.y + b0.y;
  xw[2] = (v0.z - mu) * rs * g0.z + b0.z;
  xw[3] = (v0.w - mu) * rs * g0.w + b0.w;
  xw[4] = (v1.x - mu) * rs * g1.x + b1.x;
  xw[5] = (v1.y - mu) * rs * g1.y + b1.y;
  xw[6] = (v1.z - mu) * rs * g1.z + b1.z;
  xw[7] = (v1.w - mu) * rs * g1.w + b1.w;
  __syncthreads();

  int e = tid;                       // 256 output columns
  float acc[32];
#pragma unroll
  for (int r2 = 0; r2 < 32; r2++) acc[r2] = 0.f;
  const float4* Wv = (const float4*)(W + e * 64);
#pragma unroll
  for (int k = 0; k < 16; k++) {
    float4 w = Wv[k];
#pragma unroll
    for (int r2 = 0; r2 < 32; r2++) {
      const float4 xv = *(const float4*)&xl[r2 * 68 + k * 4];
      acc[r2] = fmaf(w.x, xv.x, fmaf(w.y, xv.y, fmaf(w.z, xv.z, fmaf(w.w, xv.w, acc[r2]))));
    }
  }
  float* xo = xz + (size_t)blockIdx.x * 32 * 256 + e;
#pragma unroll
  for (int r2 = 0; r2 < 32; r2++) xo[r2 * 256] = acc[r2];
}

// ------------- conv+silu+x_dbl+softplus: writes us, dadb=(delta,delta*u), bc=(B,C) -------------
__global__ __launch_bounds__(256) void k_conv_xdbl(
    const float* __restrict__ xz, const float* __restrict__ cw,
    const float* __restrict__ cb, const float* __restrict__ Wx,
    const float* __restrict__ Wdt, const float* __restrict__ bdt,
    float* __restrict__ us, float* __restrict__ dadb, float* __restrict__ bc) {
  __shared__ float Wxl[36 * 132];
  __shared__ float usl[8 * 132];
  __shared__ float uh[11 * 128];
  __shared__ float xdl[8 * 8];
  int tid = threadIdx.x;
  int b = blockIdx.x >> 8;           // 256 l-chunks per b
  int l0 = (blockIdx.x & 255) * 8;

  for (int i = tid; i < 36 * 128; i += 256)
    Wxl[(i >> 7) * 132 + (i & 127)] = Wx[i];
  for (int i = tid; i < 11 * 128; i += 256) {
    int rr = i >> 7, e2 = i & 127;
    int gl = l0 + rr - 3;
    uh[i] = (gl >= 0) ? xz[((size_t)(b * L_ + gl)) * 256 + e2] : 0.f;
  }
  __syncthreads();

  int e = tid & 127, sub = tid >> 7;
  const float4 cwv = *(const float4*)(cw + e * 4);
  float cbv = cb[e];
#pragma unroll
  for (int rr = 0; rr < 4; rr++) {
    int row = sub * 4 + rr;
    float uc = cbv + uh[row * 128 + e] * cwv.x + uh[(row + 1) * 128 + e] * cwv.y
             + uh[(row + 2) * 128 + e] * cwv.z + uh[(row + 3) * 128 + e] * cwv.w;
    float sg = 1.f / (1.f + __expf(-uc));
    float uv = uc * sg;
    usl[row * 132 + e] = uv;
    us[((size_t)(b * L_ + l0 + row)) * 128 + e] = uv;
  }
  __syncthreads();

  for (int o = tid; o < 288; o += 256) {    // 8 rows x 36 x_dbl outputs
    int row = o / 36;
    int r = o - row * 36;
    const float* up = &usl[row * 132];
    const float* wp = &Wxl[r * 132];
    int rot = (r & 1) << 2;                 // bank de-conflict rotation
    float a0 = 0.f, a1 = 0.f, a2 = 0.f, a3 = 0.f;
#pragma unroll
    for (int i = 0; i < 32; i++) {
      int c = (i + rot) & 31;
      float4 u4 = *(const float4*)(up + c * 4);
      float4 w4 = *(const float4*)(wp + c * 4);
      a0 = fmaf(u4.x, w4.x, a0); a1 = fmaf(u4.y, w4.y, a1);
      a2 = fmaf(u4.z, w4.z, a2); a3 = fmaf(u4.w, w4.w, a3);
    }
    float acc = (a0 + a1) + (a2 + a3);
    int l = l0 + row;
    if (r < 4)        xdl[row * 8 + r] = acc;
    else if (r < 20)  bc[(((size_t)(b * L_ + l)) * 16 + (r - 4)) * 2] = acc;
    else              bc[(((size_t)(b * L_ + l)) * 16 + (r - 20)) * 2 + 1] = acc;
  }
  __syncthreads();

  const float4 wdt = *(const float4*)(Wdt + e * 4);
  float bd = bdt[e];
  float2* dadb2 = (float2*)dadb;
#pragma unroll
  for (int rr = 0; rr < 4; rr++) {
    int row = sub * 4 + rr;
    float pre = bd + xdl[row * 8 + 0] * wdt.x + xdl[row * 8 + 1] * wdt.y
              + xdl[row * 8 + 2] * wdt.z + xdl[row * 8 + 3] * wdt.w;
    float ex = __expf(pre);
    float sp = (pre > 20.f) ? pre : __logf(1.f + ex);
    float uv = usl[row * 132 + e];
    dadb2[((size_t)(b * L_ + l0 + row)) * 128 + e] = make_float2(sp, sp * uv);
  }
}

// ---------------- selective scan: 16 lanes per (b,e), DPP reduce, ys -> xz u-half ----------------
__global__ __launch_bounds__(256) void k_scan(
    const float* __restrict__ dadb, const float* __restrict__ bc,
    const float* __restrict__ Alog, float* __restrict__ ys) {
  int tid = threadIdx.x;
  int g = tid >> 4, n = tid & 15;
  int b = blockIdx.x >> 3;
  int e = (blockIdx.x & 7) * 16 + g;
  float A2 = -__expf(Alog[e * 16 + n]) * 1.44269504088896f;  // A * log2(e)
  const float2* dp = (const float2*)dadb + (size_t)b * L_ * 128 + e;
  const float2* bp = (const float2*)bc + (size_t)b * L_ * 16 + n;
  float* yp = ys + (size_t)b * L_ * 256 + e;
  float hst = 0.f;
  for (int t0 = 0; t0 < L_; t0 += 16) {
    float yv[16];
#pragma unroll
    for (int k = 0; k < 16; k++) {
      float2 dd = dp[(size_t)(t0 + k) * 128];
      float2 cv = bp[(size_t)(t0 + k) * 16];
      float a = exp2f(dd.x * A2);
      hst = fmaf(a, hst, dd.y * cv.x);
      float p = hst * cv.y;
      DPPADD(p, 0x111);  // row_shr:1
      DPPADD(p, 0x112);  // row_shr:2
      DPPADD(p, 0x114);  // row_shr:4
      DPPADD(p, 0x118);  // row_shr:8  -> lane15 holds sum
      yv[k] = p;
    }
    if (n == 15) {
#pragma unroll
      for (int k = 0; k < 16; k++) yp[(size_t)(t0 + k) * 256] = yv[k];
    }
  }
}

// ---------------- out GEMM: h += ((ys + us*Dp) * silu(z)) @ W_out^T ----------------
__global__ __launch_bounds__(256) void k_out(
    const float* __restrict__ xz, const float* __restrict__ us,
    const float* __restrict__ Dp, const float* __restrict__ W,
    float* __restrict__ h) {
  __shared__ float yl[64 * 132];
  int tid = threadIdx.x;
  size_t r0 = (size_t)blockIdx.x * 64;
  for (int i = tid; i < 64 * 128; i += 256) {
    int row = i >> 7, e = i & 127;
    size_t gr = r0 + row;
    float yv = xz[gr * 256 + e];          // ys aliased into u-half
    float uv = us[gr * 128 + e];
    float z  = xz[gr * 256 + 128 + e];
    float sg = 1.f / (1.f + __expf(-z));
    yl[row * 132 + e] = (yv + uv * Dp[e]) * z * sg;
  }
  __syncthreads();
  int c = tid & 63, rg = tid >> 6;
  float acc[16];
#pragma unroll
  for (int r = 0; r < 16; r++) acc[r] = 0.f;
  const float4* Wv = (const float4*)(W + c * 128);
#pragma unroll
  for (int k = 0; k < 32; k++) {
    float4 w = Wv[k];
#pragma unroll
    for (int r = 0; r < 16; r++) {
      float4 yv = *(const float4*)&yl[(rg * 16 + r) * 132 + k * 4];
      acc[r] = fmaf(w.x, yv.x, fmaf(w.y, yv.y, fmaf(w.z, yv.z, fmaf(w.w, yv.w, acc[r]))));
    }
  }
#pragma unroll
  for (int r = 0; r < 16; r++) {
    size_t idx = (r0 + rg * 16 + r) * 64 + c;
    h[idx] += acc[r];
  }
}

// ---------------- head: mean over L then tiny GEMM ----------------
__global__ void k_mean(const float* __restrict__ h, float* __restrict__ mean) {
  int b = blockIdx.x >> 5, lc = blockIdx.x & 31;
  int d = threadIdx.x;
  const float* p = h + ((size_t)(b * L_ + lc * 64)) * 64 + d;
  float s = 0.f;
#pragma unroll 8
  for (int i = 0; i < 64; i++) s += p[i * 64];
  atomicAdd(mean + b * 64 + d, s * (1.f / 2048.f));
}

__global__ void k_head(const float* __restrict__ mean, const float* __restrict__ Wh,
                       const float* __restrict__ bh, float* __restrict__ out) {
  int i = threadIdx.x;
  if (i >= B_ * NCLS) return;
  int b = i / NCLS, c = i - b * NCLS;
  const float* m = mean + b * 64;
  const float* w = Wh + c * 64;
  float acc = bh[c];
#pragma unroll
  for (int d = 0; d < 64; d++) acc = fmaf(m[d], w[d], acc);
  out[i] = acc;
}

extern "C" void kernel_launch(void* const* d_in, const int* in_sizes, int n_in,
                              void* d_out, int out_size, void* d_ws, size_t ws_size,
                              hipStream_t stream) {
  const float* x     = (const float*)d_in[0];
  const float* Wp    = (const float*)d_in[1];
  const float* bp    = (const float*)d_in[2];
  const float* lng   = (const float*)d_in[3];
  const float* lnb   = (const float*)d_in[4];
  const float* Win   = (const float*)d_in[5];
  const float* cw    = (const float*)d_in[6];
  const float* cb    = (const float*)d_in[7];
  const float* Wx    = (const float*)d_in[8];
  const float* Wdt   = (const float*)d_in[9];
  const float* bdt   = (const float*)d_in[10];
  const float* Alog  = (const float*)d_in[11];
  const float* Dp    = (const float*)d_in[12];
  const float* Wout  = (const float*)d_in[13];
  const float* Whead = (const float*)d_in[14];
  const float* bhead = (const float*)d_in[15];
  float* out = (float*)d_out;
  float* w = (float*)d_ws;

  float* h    = w;                 // BL*64   = 2097152
  float* xz   = w + 2097152;       // BL*256  = 8388608 (ys aliases u-half after scan)
  float* us   = w + 10485760;      // BL*128  = 4194304
  float* dadb = w + 14680064;      // BL*128*2= 8388608
  float* bc   = w + 23068672;      // BL*16*2 = 1048576
  float* mean = w + 24117248;      // 1024

  k_init<<<8192, 256, 0, stream>>>(x, Wp, bp, h, mean);
  for (int l = 0; l < NLAY; l++) {
    k_lnxz<<<1024, 256, 0, stream>>>(h, lng + l * 64, lnb + l * 64,
                                     Win + l * 256 * 64, xz);
    k_conv_xdbl<<<4096, 256, 0, stream>>>(xz, cw + l * 128 * 4, cb + l * 128,
                                          Wx + l * 36 * 128, Wdt + l * 128 * 4,
                                          bdt + l * 128, us, dadb, bc);
    k_scan<<<128, 256, 0, stream>>>(dadb, bc, Alog + l * 128 * 16, xz);
    k_out<<<512, 256, 0, stream>>>(xz, us, Dp + l * 128, Wout + l * 64 * 128, h);
  }
  k_mean<<<512, 64, 0, stream>>>(h, mean);
  k_head<<<1, 576, 0, stream>>>(mean, Whead, bhead, out);
}

// Round 2
// 914.133 us; speedup vs baseline: 1.4813x; 1.4813x over previous
//
#include <hip/hip_runtime.h>
#include <math.h>

#define B_   16
#define L_   2048
#define DMOD 64
#define E_   128
#define S_   16
#define NLAY 4
#define NCLS 35
#define NC   16      // scan chunks
#define CL   128     // chunk length (NC*CL == L_)
// BL = 32768

// DPP row_shr add: invalid lanes contribute 0 (bound_ctrl=true, old=0)
#define DPPADD(x, ctrl) \
  x += __int_as_float(__builtin_amdgcn_update_dpp(0, __float_as_int(x), ctrl, 0xf, 0xf, true))

// ---------------- init: h = x*W_proj + b_proj ; zero mean ----------------
__global__ void k_init(const float* __restrict__ x, const float* __restrict__ Wp,
                       const float* __restrict__ bp, float* __restrict__ h,
                       float* __restrict__ mean) {
  int i = blockIdx.x * 256 + threadIdx.x;   // grid covers BL*64 exactly
  if (i < B_ * DMOD) mean[i] = 0.f;
  int d = i & 63;
  int r = i >> 6;
  h[i] = x[r] * Wp[d] + bp[d];
}

// ---------------- LN + xz GEMM: xz[r,e] = sum_d LN(h)[r,d] * W_in[e,d] ----------------
__global__ __launch_bounds__(256) void k_lnxz(
    const float* __restrict__ h, const float* __restrict__ lgm,
    const float* __restrict__ lbt, const float* __restrict__ W,
    float* __restrict__ xz) {
  __shared__ float xl[32 * 68];
  int tid = threadIdx.x;
  int row = tid >> 3, j = tid & 7;
  size_t gr = (size_t)blockIdx.x * 32 + row;
  const float4* hp = (const float4*)(h + gr * 64 + j * 8);
  float4 v0 = hp[0], v1 = hp[1];
  float s = v0.x + v0.y + v0.z + v0.w + v1.x + v1.y + v1.z + v1.w;
  s += __shfl_xor(s, 1, 8); s += __shfl_xor(s, 2, 8); s += __shfl_xor(s, 4, 8);
  float mu = s * (1.f / 64.f);
  float d0, q = 0.f;
  d0 = v0.x - mu; q += d0 * d0;  d0 = v0.y - mu; q += d0 * d0;
  d0 = v0.z - mu; q += d0 * d0;  d0 = v0.w - mu; q += d0 * d0;
  d0 = v1.x - mu; q += d0 * d0;  d0 = v1.y - mu; q += d0 * d0;
  d0 = v1.z - mu; q += d0 * d0;  d0 = v1.w - mu; q += d0 * d0;
  q += __shfl_xor(q, 1, 8); q += __shfl_xor(q, 2, 8); q += __shfl_xor(q, 4, 8);
  float rs = rsqrtf(q * (1.f / 64.f) + 1e-5f);
  const float4* gp = (const float4*)(lgm + j * 8);
  const float4* bp2 = (const float4*)(lbt + j * 8);
  float4 g0 = gp[0], g1 = gp[1], b0 = bp2[0], b1 = bp2[1];
  float* xw = &xl[row * 68 + j * 8];
  xw[0] = (v0.x - mu) * rs * g0.x + b0.x;
  xw[1] = (v0.y - mu) * rs * g0.y + b0.y;
  xw[2] = (v0.z - mu) * rs * g0.z + b0.z;
  xw[3] = (v0.w - mu) * rs * g0.w + b0.w;
  xw[4] = (v1.x - mu) * rs * g1.x + b1.x;
  xw[5] = (v1.y - mu) * rs * g1.y + b1.y;
  xw[6] = (v1.z - mu) * rs * g1.z + b1.z;
  xw[7] = (v1.w - mu) * rs * g1.w + b1.w;
  __syncthreads();

  int e = tid;                       // 256 output columns
  float acc[32];
#pragma unroll
  for (int r2 = 0; r2 < 32; r2++) acc[r2] = 0.f;
  const float4* Wv = (const float4*)(W + e * 64);
#pragma unroll
  for (int k = 0; k < 16; k++) {
    float4 w = Wv[k];
#pragma unroll
    for (int r2 = 0; r2 < 32; r2++) {
      const float4 xv = *(const float4*)&xl[r2 * 68 + k * 4];
      acc[r2] = fmaf(w.x, xv.x, fmaf(w.y, xv.y, fmaf(w.z, xv.z, fmaf(w.w, xv.w, acc[r2]))));
    }
  }
  float* xo = xz + (size_t)blockIdx.x * 32 * 256 + e;
#pragma unroll
  for (int r2 = 0; r2 < 32; r2++) xo[r2 * 256] = acc[r2];
}

// ------------- conv+silu+x_dbl+softplus: writes us, dadb=(delta,delta*u), bc=(B,C) -------------
__global__ __launch_bounds__(256) void k_conv_xdbl(
    const float* __restrict__ xz, const float* __restrict__ cw,
    const float* __restrict__ cb, const float* __restrict__ Wx,
    const float* __restrict__ Wdt, const float* __restrict__ bdt,
    float* __restrict__ us, float* __restrict__ dadb, float* __restrict__ bc) {
  __shared__ float Wxl[36 * 132];
  __shared__ float usl[8 * 132];
  __shared__ float uh[11 * 128];
  __shared__ float xdl[8 * 8];
  int tid = threadIdx.x;
  int b = blockIdx.x >> 8;           // 256 l-chunks per b
  int l0 = (blockIdx.x & 255) * 8;

  for (int i = tid; i < 36 * 128; i += 256)
    Wxl[(i >> 7) * 132 + (i & 127)] = Wx[i];
  for (int i = tid; i < 11 * 128; i += 256) {
    int rr = i >> 7, e2 = i & 127;
    int gl = l0 + rr - 3;
    uh[i] = (gl >= 0) ? xz[((size_t)(b * L_ + gl)) * 256 + e2] : 0.f;
  }
  __syncthreads();

  int e = tid & 127, sub = tid >> 7;
  const float4 cwv = *(const float4*)(cw + e * 4);
  float cbv = cb[e];
#pragma unroll
  for (int rr = 0; rr < 4; rr++) {
    int row = sub * 4 + rr;
    float uc = cbv + uh[row * 128 + e] * cwv.x + uh[(row + 1) * 128 + e] * cwv.y
             + uh[(row + 2) * 128 + e] * cwv.z + uh[(row + 3) * 128 + e] * cwv.w;
    float sg = 1.f / (1.f + __expf(-uc));
    float uv = uc * sg;
    usl[row * 132 + e] = uv;
    us[((size_t)(b * L_ + l0 + row)) * 128 + e] = uv;
  }
  __syncthreads();

  for (int o = tid; o < 288; o += 256) {    // 8 rows x 36 x_dbl outputs
    int row = o / 36;
    int r = o - row * 36;
    const float* up = &usl[row * 132];
    const float* wp = &Wxl[r * 132];
    int rot = (r & 1) << 2;                 // bank de-conflict rotation
    float a0 = 0.f, a1 = 0.f, a2 = 0.f, a3 = 0.f;
#pragma unroll
    for (int i = 0; i < 32; i++) {
      int c = (i + rot) & 31;
      float4 u4 = *(const float4*)(up + c * 4);
      float4 w4 = *(const float4*)(wp + c * 4);
      a0 = fmaf(u4.x, w4.x, a0); a1 = fmaf(u4.y, w4.y, a1);
      a2 = fmaf(u4.z, w4.z, a2); a3 = fmaf(u4.w, w4.w, a3);
    }
    float acc = (a0 + a1) + (a2 + a3);
    int l = l0 + row;
    if (r < 4)        xdl[row * 8 + r] = acc;
    else if (r < 20)  bc[(((size_t)(b * L_ + l)) * 16 + (r - 4)) * 2] = acc;
    else              bc[(((size_t)(b * L_ + l)) * 16 + (r - 20)) * 2 + 1] = acc;
  }
  __syncthreads();

  const float4 wdt = *(const float4*)(Wdt + e * 4);
  float bd = bdt[e];
  float2* dadb2 = (float2*)dadb;
#pragma unroll
  for (int rr = 0; rr < 4; rr++) {
    int row = sub * 4 + rr;
    float pre = bd + xdl[row * 8 + 0] * wdt.x + xdl[row * 8 + 1] * wdt.y
              + xdl[row * 8 + 2] * wdt.z + xdl[row * 8 + 3] * wdt.w;
    float ex = __expf(pre);
    float sp = (pre > 20.f) ? pre : __logf(1.f + ex);
    float uv = usl[row * 132 + e];
    dadb2[((size_t)(b * L_ + l0 + row)) * 128 + e] = make_float2(sp, sp * uv);
  }
}

// ---------------- scan pass 1: per-chunk local (decay product P, end state E) ----------------
// block = (b, eg, c); 16 lanes per channel e=eg*16+g, lane n = state index
__global__ __launch_bounds__(256) void k_scan1(
    const float* __restrict__ dadb, const float* __restrict__ bc,
    const float* __restrict__ Alog, float2* __restrict__ PE) {
  int tid = threadIdx.x;
  int g = tid >> 4, n = tid & 15;
  int b = blockIdx.x >> 7;
  int eg = (blockIdx.x >> 4) & 7;
  int c = blockIdx.x & 15;
  int e = eg * 16 + g;
  float A2 = -__expf(Alog[e * 16 + n]) * 1.44269504088896f;
  const float2* dp = (const float2*)dadb + (size_t)(b * L_ + c * CL) * 128 + e;
  const float2* bp = (const float2*)bc + (size_t)(b * L_ + c * CL) * 16 + n;
  float P = 1.f, hst = 0.f;
  for (int t0 = 0; t0 < CL; t0 += 8) {
#pragma unroll
    for (int k = 0; k < 8; k++) {
      float2 dd = dp[(size_t)(t0 + k) * 128];
      float2 cv = bp[(size_t)(t0 + k) * 16];
      float a = exp2f(dd.x * A2);
      P *= a;
      hst = fmaf(a, hst, dd.y * cv.x);
    }
  }
  // layout [c][b*2048 + eg*256 + tid] -> coalesced per block
  PE[(size_t)c * 32768 + ((blockIdx.x >> 4) << 8) + tid] = make_float2(P, hst);
}

// ---------------- scan pass 2: sequential combine over chunks (tiny) ----------------
__global__ __launch_bounds__(256) void k_scan2(const float2* __restrict__ PE,
                                               float* __restrict__ HS) {
  int i = blockIdx.x * 256 + threadIdx.x;   // 32768 channels*states
  float H = 0.f;
#pragma unroll
  for (int c = 0; c < NC; c++) {
    float2 pe = PE[(size_t)c * 32768 + i];
    HS[(size_t)c * 32768 + i] = H;          // start state for chunk c
    H = fmaf(pe.x, H, pe.y);
  }
}

// ---------------- scan pass 3: seeded local scan, emits y -> xz u-half ----------------
__global__ __launch_bounds__(256) void k_scan3(
    const float* __restrict__ dadb, const float* __restrict__ bc,
    const float* __restrict__ Alog, const float* __restrict__ HS,
    float* __restrict__ ys) {
  int tid = threadIdx.x;
  int g = tid >> 4, n = tid & 15;
  int b = blockIdx.x >> 7;
  int eg = (blockIdx.x >> 4) & 7;
  int c = blockIdx.x & 15;
  int e = eg * 16 + g;
  float A2 = -__expf(Alog[e * 16 + n]) * 1.44269504088896f;
  const float2* dp = (const float2*)dadb + (size_t)(b * L_ + c * CL) * 128 + e;
  const float2* bp = (const float2*)bc + (size_t)(b * L_ + c * CL) * 16 + n;
  float* yp = ys + (size_t)(b * L_ + c * CL) * 256 + e;
  float hst = HS[(size_t)c * 32768 + ((blockIdx.x >> 4) << 8) + tid];
  for (int t0 = 0; t0 < CL; t0 += 16) {
    float yv[16];
#pragma unroll
    for (int k = 0; k < 16; k++) {
      float2 dd = dp[(size_t)(t0 + k) * 128];
      float2 cv = bp[(size_t)(t0 + k) * 16];
      float a = exp2f(dd.x * A2);
      hst = fmaf(a, hst, dd.y * cv.x);
      float p = hst * cv.y;
      DPPADD(p, 0x111);  // row_shr:1
      DPPADD(p, 0x112);  // row_shr:2
      DPPADD(p, 0x114);  // row_shr:4
      DPPADD(p, 0x118);  // row_shr:8  -> lane15 holds sum
      yv[k] = p;
    }
    if (n == 15) {
#pragma unroll
      for (int k = 0; k < 16; k++) yp[(size_t)(t0 + k) * 256] = yv[k];
    }
  }
}

// ---------------- out GEMM: h += ((ys + us*Dp) * silu(z)) @ W_out^T ----------------
__global__ __launch_bounds__(256) void k_out(
    const float* __restrict__ xz, const float* __restrict__ us,
    const float* __restrict__ Dp, const float* __restrict__ W,
    float* __restrict__ h) {
  __shared__ float yl[64 * 132];
  int tid = threadIdx.x;
  size_t r0 = (size_t)blockIdx.x * 64;
  for (int i = tid; i < 64 * 128; i += 256) {
    int row = i >> 7, e = i & 127;
    size_t gr = r0 + row;
    float yv = xz[gr * 256 + e];          // ys aliased into u-half
    float uv = us[gr * 128 + e];
    float z  = xz[gr * 256 + 128 + e];
    float sg = 1.f / (1.f + __expf(-z));
    yl[row * 132 + e] = (yv + uv * Dp[e]) * z * sg;
  }
  __syncthreads();
  int c = tid & 63, rg = tid >> 6;
  float acc[16];
#pragma unroll
  for (int r = 0; r < 16; r++) acc[r] = 0.f;
  const float4* Wv = (const float4*)(W + c * 128);
#pragma unroll
  for (int k = 0; k < 32; k++) {
    float4 w = Wv[k];
#pragma unroll
    for (int r = 0; r < 16; r++) {
      float4 yv = *(const float4*)&yl[(rg * 16 + r) * 132 + k * 4];
      acc[r] = fmaf(w.x, yv.x, fmaf(w.y, yv.y, fmaf(w.z, yv.z, fmaf(w.w, yv.w, acc[r]))));
    }
  }
#pragma unroll
  for (int r = 0; r < 16; r++) {
    size_t idx = (r0 + rg * 16 + r) * 64 + c;
    h[idx] += acc[r];
  }
}

// ---------------- head: mean over L then tiny GEMM ----------------
__global__ void k_mean(const float* __restrict__ h, float* __restrict__ mean) {
  int b = blockIdx.x >> 5, lc = blockIdx.x & 31;
  int d = threadIdx.x;
  const float* p = h + ((size_t)(b * L_ + lc * 64)) * 64 + d;
  float s = 0.f;
#pragma unroll 8
  for (int i = 0; i < 64; i++) s += p[i * 64];
  atomicAdd(mean + b * 64 + d, s * (1.f / 2048.f));
}

__global__ void k_head(const float* __restrict__ mean, const float* __restrict__ Wh,
                       const float* __restrict__ bh, float* __restrict__ out) {
  int i = threadIdx.x;
  if (i >= B_ * NCLS) return;
  int b = i / NCLS, c = i - b * NCLS;
  const float* m = mean + b * 64;
  const float* w = Wh + c * 64;
  float acc = bh[c];
#pragma unroll
  for (int d = 0; d < 64; d++) acc = fmaf(m[d], w[d], acc);
  out[i] = acc;
}

extern "C" void kernel_launch(void* const* d_in, const int* in_sizes, int n_in,
                              void* d_out, int out_size, void* d_ws, size_t ws_size,
                              hipStream_t stream) {
  const float* x     = (const float*)d_in[0];
  const float* Wp    = (const float*)d_in[1];
  const float* bp    = (const float*)d_in[2];
  const float* lng   = (const float*)d_in[3];
  const float* lnb   = (const float*)d_in[4];
  const float* Win   = (const float*)d_in[5];
  const float* cw    = (const float*)d_in[6];
  const float* cb    = (const float*)d_in[7];
  const float* Wx    = (const float*)d_in[8];
  const float* Wdt   = (const float*)d_in[9];
  const float* bdt   = (const float*)d_in[10];
  const float* Alog  = (const float*)d_in[11];
  const float* Dp    = (const float*)d_in[12];
  const float* Wout  = (const float*)d_in[13];
  const float* Whead = (const float*)d_in[14];
  const float* bhead = (const float*)d_in[15];
  float* out = (float*)d_out;
  float* w = (float*)d_ws;

  float* h    = w;                 // BL*64   = 2097152
  float* xz   = w + 2097152;       // BL*256  = 8388608 (ys aliases u-half after scan)
  float* us   = w + 10485760;      // BL*128  = 4194304
  float* dadb = w + 14680064;      // BL*128*2= 8388608
  float* bc   = w + 23068672;      // BL*16*2 = 1048576
  float* mean = w + 24117248;      // 1024
  float2* PE  = (float2*)(w + 24118272);  // 32768*NC float2 = 1048576 floats
  float* HS   = w + 25166848;      // 32768*NC = 524288 floats

  k_init<<<8192, 256, 0, stream>>>(x, Wp, bp, h, mean);
  for (int l = 0; l < NLAY; l++) {
    k_lnxz<<<1024, 256, 0, stream>>>(h, lng + l * 64, lnb + l * 64,
                                     Win + l * 256 * 64, xz);
    k_conv_xdbl<<<4096, 256, 0, stream>>>(xz, cw + l * 128 * 4, cb + l * 128,
                                          Wx + l * 36 * 128, Wdt + l * 128 * 4,
                                          bdt + l * 128, us, dadb, bc);
    k_scan1<<<2048, 256, 0, stream>>>(dadb, bc, Alog + l * 128 * 16, PE);
    k_scan2<<<128, 256, 0, stream>>>(PE, HS);
    k_scan3<<<2048, 256, 0, stream>>>(dadb, bc, Alog + l * 128 * 16, HS, xz);
    k_out<<<512, 256, 0, stream>>>(xz, us, Dp + l * 128, Wout + l * 64 * 128, h);
  }
  k_mean<<<512, 64, 0, stream>>>(h, mean);
  k_head<<<1, 576, 0, stream>>>(mean, Whead, bhead, out);
}